// Round 1
// baseline (146.160 us; speedup 1.0000x reference)
//
#include <hip/hip_runtime.h>

// N=16384 rows, D=1024 fp32. loss = mean_r(1 - cos(pc[r], aug[r]))
// R2: one-row-per-wave was latency-bound (VALUBusy 8.7%, HBM 20%): the 6-deep
// shfl reduce chain (~240 cy serial) ran with zero outstanding loads, halving
// the memory-pipe duty cycle. Fix: 4 rows per wave, 2-deep register double
// buffer -> row i+1's 8 loads are in flight during row i's reduce.
// 1024 blocks x 4 waves = 16 waves/CU, fully resident (no block churn).

#define N_ROWS 16384
#define DIM_V4 256              // 1024 floats = 256 float4
#define TPB 256
#define WAVES_PER_BLOCK (TPB / 64)
#define ROWS_PER_WAVE 4
#define ROWS_PER_BLOCK (WAVES_PER_BLOCK * ROWS_PER_WAVE)   // 16
#define BLOCKS (N_ROWS / ROWS_PER_BLOCK)                   // 1024

// __launch_bounds__(256, 4): 4 waves/SIMD -> caps regalloc at 128 VGPR so all
// 16 waves/CU stay resident (data alone is 64 VGPR: 2 bufs x 8 float4).
__global__ __launch_bounds__(TPB, 4) void cos_rows_kernel(
    const float4* __restrict__ a, const float4* __restrict__ b,
    float* __restrict__ partial)
{
    const int wave = threadIdx.x >> 6;
    const int lane = threadIdx.x & 63;
    const int gw = blockIdx.x * WAVES_PER_BLOCK + wave;   // global wave id
    const size_t base = (size_t)gw * ROWS_PER_WAVE * DIM_V4 + lane;
    const float4* ap = a + base;
    const float4* bp = b + base;

    float4 xa[4], ya[4], xb[4], yb[4];
    float wsum = 0.0f;   // lane0: sum of this wave's 4 cosines

#define LOAD_ROW(X, Y, RI) do {                                         \
    const float4* _ar = ap + (RI) * DIM_V4;                             \
    const float4* _br = bp + (RI) * DIM_V4;                             \
    _Pragma("unroll") for (int k = 0; k < 4; ++k) X[k] = _ar[64 * k];   \
    _Pragma("unroll") for (int k = 0; k < 4; ++k) Y[k] = _br[64 * k];   \
} while (0)

#define DOT_ROW(X, Y) do {                                              \
    float ab = 0.f, aa = 0.f, bb = 0.f;                                 \
    _Pragma("unroll") for (int k = 0; k < 4; ++k) {                     \
        ab += X[k].x * Y[k].x + X[k].y * Y[k].y                         \
            + X[k].z * Y[k].z + X[k].w * Y[k].w;                        \
        aa += X[k].x * X[k].x + X[k].y * X[k].y                         \
            + X[k].z * X[k].z + X[k].w * X[k].w;                        \
        bb += Y[k].x * Y[k].x + Y[k].y * Y[k].y                         \
            + Y[k].z * Y[k].z + Y[k].w * Y[k].w;                        \
    }                                                                   \
    _Pragma("unroll") for (int off = 32; off > 0; off >>= 1) {          \
        ab += __shfl_down(ab, off);                                     \
        aa += __shfl_down(aa, off);                                     \
        bb += __shfl_down(bb, off);                                     \
    }                                                                   \
    if (lane == 0) {                                                    \
        float na = fmaxf(sqrtf(aa), 1e-12f);                            \
        float nb = fmaxf(sqrtf(bb), 1e-12f);                            \
        wsum += ab / (na * nb);                                         \
    }                                                                   \
} while (0)

    // Software pipeline: next row's loads issue before current row's reduce.
    // (WAR on the buffer forces loads after the FMA reads, but the compiler
    // can hoist them above the ~240-cycle shfl chain.)
    LOAD_ROW(xa, ya, 0);
    LOAD_ROW(xb, yb, 1);
    DOT_ROW(xa, ya);
    LOAD_ROW(xa, ya, 2);
    DOT_ROW(xb, yb);
    LOAD_ROW(xb, yb, 3);
    DOT_ROW(xa, ya);
    DOT_ROW(xb, yb);

#undef LOAD_ROW
#undef DOT_ROW

    __shared__ float s[WAVES_PER_BLOCK];
    if (lane == 0) s[wave] = wsum;
    __syncthreads();
    if (threadIdx.x == 0) {
        float t = 0.0f;
        #pragma unroll
        for (int i = 0; i < WAVES_PER_BLOCK; ++i) t += s[i];
        partial[blockIdx.x] = t;
    }
}

__global__ __launch_bounds__(1024) void finalize_kernel(
    const float* __restrict__ partial, float* __restrict__ out)
{
    const int wave = threadIdx.x >> 6;
    const int lane = threadIdx.x & 63;
    float t = partial[threadIdx.x];          // BLOCKS == 1024 partials
    #pragma unroll
    for (int off = 32; off > 0; off >>= 1) t += __shfl_down(t, off);
    __shared__ float s[1024 / 64];
    if (lane == 0) s[wave] = t;
    __syncthreads();
    if (threadIdx.x == 0) {
        float tot = 0.0f;
        #pragma unroll
        for (int i = 0; i < 1024 / 64; ++i) tot += s[i];
        out[0] = 1.0f - tot / (float)N_ROWS;
    }
}

extern "C" void kernel_launch(void* const* d_in, const int* in_sizes, int n_in,
                              void* d_out, int out_size, void* d_ws, size_t ws_size,
                              hipStream_t stream) {
    const float4* pc  = (const float4*)d_in[0];
    const float4* aug = (const float4*)d_in[1];
    float* partial = (float*)d_ws;       // BLOCKS floats = 4 KiB scratch
    float* out = (float*)d_out;

    cos_rows_kernel<<<BLOCKS, TPB, 0, stream>>>(pc, aug, partial);
    finalize_kernel<<<1, 1024, 0, stream>>>(partial, out);
}

// Round 2
// 144.884 us; speedup vs baseline: 1.0088x; 1.0088x over previous
//
#include <hip/hip_runtime.h>

// N=16384 rows, D=1024 fp32. loss = mean_r(1 - cos(pc[r], aug[r]))
// R2 post-mortem: compiler sank all loads to just-before-use (VGPR 36) ->
// no pipeline; occupancy halved with flat time -> per-wave duty cycle is the
// limiter, not wave count. R3: force the 2-deep pipeline with
// __builtin_amdgcn_sched_barrier(0) after each load group (rule #18-style
// pinning), and batch the shuffle reduces 2 rows at a time (6 independent
// butterfly chains) to amortize the ~250cy serial chain.

#define N_ROWS 16384
#define DIM_V4 256              // 1024 floats = 256 float4
#define TPB 256
#define WPB (TPB / 64)          // 4 waves/block
#define RPW 4                   // rows per wave
#define BLOCKS (N_ROWS / (WPB * RPW))   // 1024 blocks, 16 waves/CU resident

__device__ __forceinline__ void load_row(const float4* __restrict__ p, float4 v[4]) {
    #pragma unroll
    for (int k = 0; k < 4; ++k) v[k] = p[64 * k];
}

__device__ __forceinline__ void dot_row(const float4 x[4], const float4 y[4],
                                        float& ab, float& aa, float& bb) {
    ab = 0.f; aa = 0.f; bb = 0.f;
    #pragma unroll
    for (int k = 0; k < 4; ++k) {
        ab += x[k].x * y[k].x + x[k].y * y[k].y + x[k].z * y[k].z + x[k].w * y[k].w;
        aa += x[k].x * x[k].x + x[k].y * x[k].y + x[k].z * x[k].z + x[k].w * x[k].w;
        bb += y[k].x * y[k].x + y[k].y * y[k].y + y[k].z * y[k].z + y[k].w * y[k].w;
    }
}

// Two rows' triplets reduced together: 6 independent chains -> shuffle pipe
// stays busy, one ~250cy chain latency amortized over 2 rows.
__device__ __forceinline__ void reduce2_accum(int lane,
        float ab0, float aa0, float bb0,
        float ab1, float aa1, float bb1, float& wsum) {
    #pragma unroll
    for (int off = 32; off > 0; off >>= 1) {
        ab0 += __shfl_down(ab0, off);
        aa0 += __shfl_down(aa0, off);
        bb0 += __shfl_down(bb0, off);
        ab1 += __shfl_down(ab1, off);
        aa1 += __shfl_down(aa1, off);
        bb1 += __shfl_down(bb1, off);
    }
    if (lane == 0) {
        float na0 = fmaxf(sqrtf(aa0), 1e-12f);
        float nb0 = fmaxf(sqrtf(bb0), 1e-12f);
        float na1 = fmaxf(sqrtf(aa1), 1e-12f);
        float nb1 = fmaxf(sqrtf(bb1), 1e-12f);
        wsum += ab0 / (na0 * nb0) + ab1 / (na1 * nb1);
    }
}

__global__ __launch_bounds__(TPB, 4) void cos_rows_kernel(
    const float4* __restrict__ a, const float4* __restrict__ b,
    float* __restrict__ partial)
{
    const int wave = threadIdx.x >> 6;
    const int lane = threadIdx.x & 63;
    const int gw = blockIdx.x * WPB + wave;     // global wave id
    const size_t base = (size_t)gw * RPW * DIM_V4 + lane;
    const float4* ap = a + base;
    const float4* bp = b + base;

    float4 x0[4], y0[4], x1[4], y1[4];
    float ab0, aa0, bb0, ab1, aa1, bb1;
    float wsum = 0.0f;

    // Prologue: rows 0 and 1 in flight (16 loads).
    load_row(ap + 0 * DIM_V4, x0);
    load_row(bp + 0 * DIM_V4, y0);
    load_row(ap + 1 * DIM_V4, x1);
    load_row(bp + 1 * DIM_V4, y1);
    __builtin_amdgcn_sched_barrier(0);   // pin: all 16 issued before any use

    // Consume row 0 into scalars, immediately refill buffer with row 2.
    dot_row(x0, y0, ab0, aa0, bb0);
    load_row(ap + 2 * DIM_V4, x0);
    load_row(bp + 2 * DIM_V4, y0);
    __builtin_amdgcn_sched_barrier(0);   // row-2 loads issued before reduce

    dot_row(x1, y1, ab1, aa1, bb1);
    load_row(ap + 3 * DIM_V4, x1);
    load_row(bp + 3 * DIM_V4, y1);
    __builtin_amdgcn_sched_barrier(0);   // row-3 loads issued before reduce

    // Rows 2,3 loads (~900cy) overlap this ~250cy reduce + next dot's wait.
    reduce2_accum(lane, ab0, aa0, bb0, ab1, aa1, bb1, wsum);

    dot_row(x0, y0, ab0, aa0, bb0);
    dot_row(x1, y1, ab1, aa1, bb1);
    reduce2_accum(lane, ab0, aa0, bb0, ab1, aa1, bb1, wsum);

    __shared__ float s[WPB];
    if (lane == 0) s[wave] = wsum;
    __syncthreads();
    if (threadIdx.x == 0) {
        float t = 0.0f;
        #pragma unroll
        for (int i = 0; i < WPB; ++i) t += s[i];
        partial[blockIdx.x] = t;
    }
}

__global__ __launch_bounds__(1024) void finalize_kernel(
    const float* __restrict__ partial, float* __restrict__ out)
{
    const int wave = threadIdx.x >> 6;
    const int lane = threadIdx.x & 63;
    float t = partial[threadIdx.x];          // BLOCKS == 1024 partials
    #pragma unroll
    for (int off = 32; off > 0; off >>= 1) t += __shfl_down(t, off);
    __shared__ float s[1024 / 64];
    if (lane == 0) s[wave] = t;
    __syncthreads();
    if (threadIdx.x == 0) {
        float tot = 0.0f;
        #pragma unroll
        for (int i = 0; i < 1024 / 64; ++i) tot += s[i];
        out[0] = 1.0f - tot / (float)N_ROWS;
    }
}

extern "C" void kernel_launch(void* const* d_in, const int* in_sizes, int n_in,
                              void* d_out, int out_size, void* d_ws, size_t ws_size,
                              hipStream_t stream) {
    const float4* pc  = (const float4*)d_in[0];
    const float4* aug = (const float4*)d_in[1];
    float* partial = (float*)d_ws;       // BLOCKS floats = 4 KiB scratch
    float* out = (float*)d_out;

    cos_rows_kernel<<<BLOCKS, TPB, 0, stream>>>(pc, aug, partial);
    finalize_kernel<<<1, 1024, 0, stream>>>(partial, out);
}